// Round 8
// baseline (79.352 us; speedup 1.0000x reference)
//
#include <hip/hip_runtime.h>
#include <cstdint>
#include <cstddef>

// Reference semantics: per-element fp32-rounded multiply, then a strictly
// sequential left-to-right fp32 add chain. FMA contraction changes low
// mantissa bits and flips output pulse bits -> keep contract OFF globally.
#pragma clang fp contract(off)

#define BATCH 256
#define IN_F  1024
#define OUT_F 1024

// ---------------------------------------------------------------------------
// decode: 32 pulse floats (0.0/1.0, MSB first) -> fp32 bit pattern
// ---------------------------------------------------------------------------
__device__ __forceinline__ uint32_t decode_bits(const float4* __restrict__ p) {
    uint32_t u = 0;
#pragma unroll
    for (int k = 0; k < 8; ++k) {
        float4 f = p[k];
        u = (u << 1) | ((__float_as_uint(f.x) >> 23) & 1u);
        u = (u << 1) | ((__float_as_uint(f.y) >> 23) & 1u);
        u = (u << 1) | ((__float_as_uint(f.z) >> 23) & 1u);
        u = (u << 1) | ((__float_as_uint(f.w) >> 23) & 1u);
    }
    return u;
}

// Fused decode.
// bid in [0,4096): w pulses -> wf[o][i] (natural order, fully coalesced).
// bid in [4096,4160): x pulses -> xt[i][b] via 64x64 LDS tile transpose
// (pad 65 -> conflict-free ds both directions; global reads and writes
// both coalesced).
__global__ __launch_bounds__(256) void decode_kernel(const float* __restrict__ xp,
                                                     const float* __restrict__ wp,
                                                     float* __restrict__ xt,
                                                     float* __restrict__ wf) {
    const int tid = threadIdx.x;
    const int bid = blockIdx.x;
    __shared__ float tile[64 * 65];
    if (bid < 4096) {
        int v = bid * 256 + tid;                   // v = o*IN + i
        wf[v] = __uint_as_float(decode_bits((const float4*)(wp + (size_t)v * 32)));
    } else {
        const int xb = bid - 4096;                 // 0..63
        const int b0 = (xb >> 4) * 64;             // 4 b-tiles
        const int i0 = (xb & 15) * 64;             // 16 i-tiles
#pragma unroll
        for (int rep = 0; rep < 16; ++rep) {
            int vl = rep * 256 + tid;
            int bl = vl >> 6, il = vl & 63;
            float val = __uint_as_float(decode_bits(
                (const float4*)(xp + (size_t)((b0 + bl) * 1024 + i0 + il) * 32)));
            tile[bl * 65 + il] = val;              // lane=il -> consecutive, no conflict
        }
        __syncthreads();
#pragma unroll
        for (int rep = 0; rep < 16; ++rep) {
            int f = rep * 256 + tid;
            int ip = f >> 6, bp = f & 63;          // bp = lane
            // read stride 65 -> banks (lane*65+ip)%32 distinct; write coalesced 256B
            xt[(size_t)(i0 + ip) * 256 + b0 + bp] = tile[bp * 65 + ip];
        }
    }
}

// ---------------------------------------------------------------------------
// GEMM, streaming, barrier-free hot loop. lane = batch; wave owns 2 o-rows.
// Block = 256 thr = 4 waves -> o-rows oq*8 + wv*2 + {0,1}, b = bt*64 + lane.
// Grid = 128 o-groups x 4 b-tiles = 512 blocks.
// w: wave-uniform float4 loads from readfirstlane'd row pointers -> s_load
// (no DS ops in the loop, so lgkm waits don't collide with anything).
// x: per-lane coalesced stream from xt[i][b], software-pipelined 8 groups
// (32 i) deep in registers; 4 waves/block share the stream -> L1 reuse.
// MAC: v_mul(v,s) + v_add, strict i order, contract off, acc init 0
// (0 + p == p bitwise for p != +-0; validated by harness).
// Epilogue: pack bits via 2KB LDS, one barrier, coalesced float4 writes.
// ---------------------------------------------------------------------------
__global__ __launch_bounds__(256) void gemm_encode_kernel(const float* __restrict__ xt,
                                                          const float* __restrict__ wf,
                                                          float* __restrict__ out) {
#pragma clang fp contract(off)
    const int tid  = threadIdx.x;
    const int lane = tid & 63;
    const int wv   = __builtin_amdgcn_readfirstlane(tid >> 6);
    const int oq   = blockIdx.x & 127;
    const int bt   = blockIdx.x >> 7;
    const int oa   = oq * 8 + wv * 2;

    const float4* __restrict__ wa4 = (const float4*)(wf + (size_t)oa * IN_F);
    const float4* __restrict__ wb4 = (const float4*)(wf + (size_t)(oa + 1) * IN_F);
    const float*  __restrict__ xcur = xt + bt * 64 + lane;

    float acc0 = 0.0f, acc1 = 0.0f;
    float xb[8][4];                                // 8-deep pipeline, 4 i each

#pragma unroll
    for (int s = 0; s < 8; ++s) {                  // preload groups 0..7
        xb[s][0] = xcur[0];   xb[s][1] = xcur[256];
        xb[s][2] = xcur[512]; xb[s][3] = xcur[768];
        xcur += 1024;
    }

#define MAC_GROUP(c_, s_)                                             \
    {                                                                 \
        float4 wa = wa4[c_], wb = wb4[c_];                            \
        acc0 = acc0 + (xb[s_][0] * wa.x); acc1 = acc1 + (xb[s_][0] * wb.x); \
        acc0 = acc0 + (xb[s_][1] * wa.y); acc1 = acc1 + (xb[s_][1] * wb.y); \
        acc0 = acc0 + (xb[s_][2] * wa.z); acc1 = acc1 + (xb[s_][2] * wb.z); \
        acc0 = acc0 + (xb[s_][3] * wa.w); acc1 = acc1 + (xb[s_][3] * wb.w); \
    }

#pragma unroll 8
    for (int c = 0; c < 248; ++c) {                // groups 0..247, reload +8 ahead
        const int s = c & 7;                       // static after unroll-8
        MAC_GROUP(c, s);
        xb[s][0] = xcur[0];   xb[s][1] = xcur[256];
        xb[s][2] = xcur[512]; xb[s][3] = xcur[768];
        xcur += 1024;
    }
#pragma unroll 8
    for (int c = 248; c < 256; ++c) {              // drain: groups 248..255
        const int s = c & 7;
        MAC_GROUP(c, s);
    }
#undef MAC_GROUP

    // ---- epilogue: bit-pack via LDS, one barrier, coalesced writes ----
    __shared__ uint32_t bits[8][65];               // [o_local][b_local], padded
    bits[wv * 2 + 0][lane] = __float_as_uint(acc0);
    bits[wv * 2 + 1][lane] = __float_as_uint(acc1);
    __syncthreads();

    // block output: 64 b x 8 o x 32 bits = 16384 floats; per b: 1KB contiguous.
    const size_t obase = (size_t)bt * 64 * 32768 + (size_t)oq * 8 * 32;
#pragma unroll
    for (int pass = 0; pass < 16; ++pass) {
        int f  = pass * 1024 + tid * 4;
        int bl = f >> 8;                           // 0..63
        int r  = f & 255;
        int ol = r >> 5;                           // 0..7
        int k0 = r & 31;                           // 0,4,..,28
        uint32_t u = bits[ol][bl];
        float4 v;
        v.x = (float)((u >> (31 - k0)) & 1u);
        v.y = (float)((u >> (30 - k0)) & 1u);
        v.z = (float)((u >> (29 - k0)) & 1u);
        v.w = (float)((u >> (28 - k0)) & 1u);
        *(float4*)(out + obase + (size_t)bl * 32768 + ol * 32 + k0) = v;
    }
}

extern "C" void kernel_launch(void* const* d_in, const int* in_sizes, int n_in,
                              void* d_out, int out_size, void* d_ws, size_t ws_size,
                              hipStream_t stream) {
    const float* x_pulses = (const float*)d_in[0];   // [B, IN, 32]
    const float* w_pulses = (const float*)d_in[1];   // [OUT, IN, 32]
    float* out = (float*)d_out;                      // [B, OUT, 32]

    float* xt = (float*)d_ws;                        // xt[IN][B]   : 1 MB
    float* wf = xt + (size_t)IN_F * BATCH;           // wf[OUT][IN] : 4 MB

    decode_kernel<<<4096 + 64, 256, 0, stream>>>(x_pulses, w_pulses, xt, wf);
    gemm_encode_kernel<<<512, 256, 0, stream>>>(xt, wf, out);
}

// Round 9
// 70.483 us; speedup vs baseline: 1.1258x; 1.1258x over previous
//
#include <hip/hip_runtime.h>
#include <cstdint>
#include <cstddef>

// Reference semantics: per-element fp32-rounded multiply, then a strictly
// sequential left-to-right fp32 add chain. FMA contraction changes low
// mantissa bits and flips output pulse bits -> keep contract OFF globally.
#pragma clang fp contract(off)

#define BATCH 256
#define IN_F  1024
#define OUT_F 1024

// ---------------------------------------------------------------------------
// Ballot decode: one wave decodes 64 consecutive values per chunk.
// Iteration t: 64 lanes read 64 CONSECUTIVE pulse dwords (256 B, 4 cache
// lines -> fully coalesced, unlike the old 128-B-per-lane-stride pattern
// that ran at ~1 TB/s). __ballot collects the 64 bits = 2 values; brev32
// converts MSB-first. Lane l keeps value l; one coalesced 256-B store.
// Chunks [0,4096): x -> xf[b][i] row-major.
// Chunks [4096,20480): w -> wt3 [IN/32][OUT][8 q][4 d] (same swizzled
// layout the gemm's global_load_lds staging expects; proven in R6).
// ---------------------------------------------------------------------------
__global__ __launch_bounds__(256) void decode_kernel(const float* __restrict__ xp,
                                                     const float* __restrict__ wp,
                                                     float* __restrict__ xf,
                                                     float* __restrict__ wt3) {
    const int tid  = threadIdx.x;
    const int lane = tid & 63;
    const int wv   = tid >> 6;
    const int chunk = blockIdx.x * 4 + wv;         // global wave-chunk

    uint32_t val = 0;
    if (chunk < 4096) {
        const size_t v0 = (size_t)chunk * 64;      // first value index
        const float* src = xp + v0 * 32 + lane;
#pragma unroll
        for (int t = 0; t < 32; ++t) {
            uint32_t u = __float_as_uint(src[t * 64]);
            uint64_t m = __ballot(u & 0x00800000u);        // bit23: 1.0f vs 0.0f
            uint32_t lo = __builtin_bitreverse32((uint32_t)m);
            uint32_t hi = __builtin_bitreverse32((uint32_t)(m >> 32));
            uint32_t pick = (lane & 1) ? hi : lo;
            if ((lane >> 1) == t) val = pick;
        }
        xf[v0 + lane] = __uint_as_float(val);      // coalesced 256 B
    } else {
        const int c = chunk - 4096;                // 0..16383
        const size_t v0 = (size_t)c * 64;          // = o*1024 + i0 (i0 % 64 == 0)
        const float* src = wp + v0 * 32 + lane;
#pragma unroll
        for (int t = 0; t < 32; ++t) {
            uint32_t u = __float_as_uint(src[t * 64]);
            uint64_t m = __ballot(u & 0x00800000u);
            uint32_t lo = __builtin_bitreverse32((uint32_t)m);
            uint32_t hi = __builtin_bitreverse32((uint32_t)(m >> 32));
            uint32_t pick = (lane & 1) ? hi : lo;
            if ((lane >> 1) == t) val = pick;
        }
        const int o = (int)(v0 >> 10);             // constant across wave
        const int i = (int)(v0 & 1023) + lane;
        size_t idx = (((((size_t)(i >> 5)) << 10) + o) * 8 + ((i >> 2) & 7)) * 4 + (i & 3);
        wt3[idx] = __uint_as_float(val);           // two 128-B segments
    }
}

// ---------------------------------------------------------------------------
// GEMM (verbatim from R6, the best-measured variant): block = 512 threads =
// 8 waves; 64 o (lanes) x 16 b rows (wave wv handles rows wv and wv+8).
// Grid = 256 blocks = 1 per CU. w staged in LDS per 128-i chunk (double-
// buffered, global_load_lds), bank-optimal layout [o=64][slot=8] float4,
// slot = q^(o&7). x delivered via v_readlane from per-lane dwords.
// Strict left-to-right fp32 accumulation over i; mul then add, no FMA.
// ---------------------------------------------------------------------------
__global__ __launch_bounds__(512, 1) void gemm_encode_kernel(const float* __restrict__ xf,
                                                             const float* __restrict__ wt3,
                                                             float* __restrict__ out) {
#pragma clang fp contract(off)
    const int tid  = threadIdx.x;
    const int lane = tid & 63;
    const int wv   = tid >> 6;
    const int ot   = blockIdx.x & 15;              // o-tile
    const int bt   = blockIdx.x >> 4;              // b-tile
    const int o_g  = ot * 64 + lane;
    const int b0   = bt * 16;
    const int om   = lane & 7;

    __shared__ float4 wl[2][4][64][8];             // 64 KB: [buf][sc][o][slot]

    const float* __restrict__ xr0 = xf + ((size_t)(b0 + wv) << 10);
    const float* __restrict__ xr1 = xf + ((size_t)(b0 + wv + 8) << 10);

    // staging lane mapping (linear LDS dest): thread t -> (o = t>>3, s = t&7)
    const int o_st = wv * 8 + (lane >> 3);
    const int q_st = (lane & 7) ^ (lane >> 3);     // content q for physical slot s

    auto stage = [&](int bb, int c) {
#pragma unroll
        for (int sc = 0; sc < 4; ++sc) {
            int sc_g = c * 4 + sc;
            size_t dw = (((((size_t)sc_g) << 10) + (ot * 64 + o_st)) * 8 + q_st) * 4;
            const char* g = (const char*)(wt3 + dw);
            char* d = (char*)(&wl[bb][sc][0][0]) + wv * 1024;
            __builtin_amdgcn_global_load_lds(
                (const __attribute__((address_space(1))) void*)g,
                (__attribute__((address_space(3))) void*)d, 16, 0, 0);
        }
    };

    float acc0 = 0.0f, acc1 = 0.0f;

    // xa* hold i = chunk*128 + [0,64) at lane = i; xb* hold i = +[64,128).
    auto compute = [&](int bb, float xa0, float xb0, float xa1, float xb1, bool first) {
#pragma unroll
        for (int sc = 0; sc < 4; ++sc) {
            float4 w4[8];
#pragma unroll
            for (int q = 0; q < 8; ++q) w4[q] = wl[bb][sc][lane][q ^ om];
            const bool loh = (sc < 2);             // which x register pair
            const int base = (sc & 1) * 32;        // lane base within it
#pragma unroll
            for (int q = 0; q < 8; ++q) {
                float wq[4] = {w4[q].x, w4[q].y, w4[q].z, w4[q].w};
#pragma unroll
                for (int d = 0; d < 4; ++d) {
                    const int ll = base + q * 4 + d;   // literal lane index
                    float x0 = __uint_as_float(__builtin_amdgcn_readlane(
                        __float_as_uint(loh ? xa0 : xb0), ll));
                    float x1 = __uint_as_float(__builtin_amdgcn_readlane(
                        __float_as_uint(loh ? xa1 : xb1), ll));
                    if (first && sc == 0 && q == 0 && d == 0) {
                        acc0 = x0 * wq[0];             // scan init: acc = prods[0]
                        acc1 = x1 * wq[0];
                    } else {
                        acc0 = acc0 + (x0 * wq[d]);
                        acc1 = acc1 + (x1 * wq[d]);
                    }
                }
            }
        }
    };

    // prologue: stage chunk 0 (w) and load chunk 0's x registers
    stage(0, 0);
    float xa0 = xr0[lane], xb0 = xr0[64 + lane];
    float xa1 = xr1[lane], xb1 = xr1[64 + lane];
    __syncthreads();                                // drains vmcnt before use

    int cur = 0;
#pragma unroll 1
    for (int c = 0; c < 8; ++c) {
        float na0 = 0.f, nb0 = 0.f, na1 = 0.f, nb1 = 0.f;
        if (c < 7) {
            stage(cur ^ 1, c + 1);                  // issue next w-chunk loads
            const int off = (c + 1) << 7;           // and next x-chunk loads
            na0 = xr0[off + lane]; nb0 = xr0[off + 64 + lane];
            na1 = xr1[off + lane]; nb1 = xr1[off + 64 + lane];
        }
        compute(cur, xa0, xb0, xa1, xb1, c == 0);
        __syncthreads();                            // vmcnt+lgkm drain + barrier
        xa0 = na0; xb0 = nb0; xa1 = na1; xb1 = nb1;
        cur ^= 1;
    }

    // ---- encode both accumulators back to 32 pulse floats ----
    const float accs[2] = {acc0, acc1};
#pragma unroll
    for (int r = 0; r < 2; ++r) {
        uint32_t u = __float_as_uint(accs[r]);
        int b = b0 + wv + r * 8;
        float4* dstp = (float4*)(out + (((size_t)b << 10) + o_g) * 32);
#pragma unroll
        for (int k = 0; k < 8; ++k) {
            float4 f;
            f.x = (float)((u >> (31 - 4 * k)) & 1u);
            f.y = (float)((u >> (30 - 4 * k)) & 1u);
            f.z = (float)((u >> (29 - 4 * k)) & 1u);
            f.w = (float)((u >> (28 - 4 * k)) & 1u);
            dstp[k] = f;
        }
    }
}

extern "C" void kernel_launch(void* const* d_in, const int* in_sizes, int n_in,
                              void* d_out, int out_size, void* d_ws, size_t ws_size,
                              hipStream_t stream) {
    const float* x_pulses = (const float*)d_in[0];   // [B, IN, 32]
    const float* w_pulses = (const float*)d_in[1];   // [OUT, IN, 32]
    float* out = (float*)d_out;                      // [B, OUT, 32]

    float* xf  = (float*)d_ws;                       // xf[B][IN]  : 1 MB
    float* wt3 = xf + (size_t)BATCH * IN_F;          // wt3 swizzl : 4 MB

    // 4096 x-chunks + 16384 w-chunks, 4 wave-chunks per block -> 5120 blocks
    decode_kernel<<<5120, 256, 0, stream>>>(x_pulses, w_pulses, xf, wt3);
    gemm_encode_kernel<<<256, 512, 0, stream>>>(xf, wt3, out);
}